// Round 17
// baseline (105.722 us; speedup 1.0000x reference)
//
#include <hip/hip_runtime.h>
#include <hip/hip_fp16.h>

typedef __attribute__((ext_vector_type(8))) _Float16 half8;
typedef __attribute__((ext_vector_type(16))) float f32x16;

union U2H2 { unsigned int u; __half2 h; };

static __device__ __forceinline__ unsigned int pack2h(float a, float b) {
    U2H2 c; c.h = __floats2half2_rn(a, b); return c.u;
}
static __device__ __forceinline__ __half2 u_as_h2(unsigned int u) {
    U2H2 c; c.u = u; return c.h;
}

// Prep: blocks [0,nT): transpose x -> xth [N][2][32] fp16 (b-halves share a
// 128B line). blocks [nT,nT+25): W -> 32x32-MFMA A-fragment order:
//   Wrh[k][chunk=og*2+cg][l][e] = half(W[o = og*32+(l&31),
//                                      (c = cg*16+(l>>5)*8+e)*25 + k])
__global__ __launch_bounds__(256) void prep_all(const float* __restrict__ x,
                                                const float* __restrict__ W,
                                                unsigned short* __restrict__ xth,
                                                unsigned short* __restrict__ Wrh,
                                                int N, int nT) {
    int bid = blockIdx.x, tid = threadIdx.x;
    if (bid >= nT) {
        int k = bid - nT;  // 0..24
#pragma unroll
        for (int it = 0; it < 8; ++it) {
            int r = tid + 256 * it;          // 0..2047 = chunk*512 + l*8 + e
            int chunk = r >> 9;
            int l = (r >> 3) & 63;
            int e = r & 7;
            int og = chunk >> 1, cg = chunk & 1;
            int o = og * 32 + (l & 31);
            int c = cg * 16 + ((l >> 5) << 3) + e;
            __half h = __float2half(W[o * 800 + c * 25 + k]);
            Wrh[k * 2048 + r] = *reinterpret_cast<unsigned short*>(&h);
        }
        return;
    }
    __shared__ float t[2][32][65];
    int n0 = bid * 64;
#pragma unroll
    for (int i = 0; i < 16; ++i) {
        int e = tid + 256 * i;               // [2][32][64]
        int b = e >> 11, c = (e >> 6) & 31, nl = e & 63;
        int n = n0 + nl;
        t[b][c][nl] = (n < N) ? x[(size_t)(b * 32 + c) * N + n] : 0.f;
    }
    __syncthreads();
    int nl = tid >> 2, q = tid & 3, n = n0 + nl;
    if (n < N) {
#pragma unroll
        for (int b = 0; b < 2; ++b) {
            uint4 p;
            p.x = pack2h(t[b][q * 8 + 0][nl], t[b][q * 8 + 1][nl]);
            p.y = pack2h(t[b][q * 8 + 2][nl], t[b][q * 8 + 3][nl]);
            p.z = pack2h(t[b][q * 8 + 4][nl], t[b][q * 8 + 5][nl]);
            p.w = pack2h(t[b][q * 8 + 6][nl], t[b][q * 8 + 7][nl]);
            *reinterpret_cast<uint4*>(xth + ((size_t)n * 64 + b * 32 + q * 8)) = p;
        }
    }
}

// Fused gather + einsum + MFMA(32x32x16, swapped operands) + bias.
// 32-n tile, 128 threads = 2 waves; wave = batch half. Lane l owns output
// column n = n0+(l&31): it gathers that row's c-slices (16B each), does the
// weighted fp16 sum in registers -> the result IS the MFMA B-fragment.
// A = W-fragments from global (L1-hot). NO LDS, NO barriers, NO fences.
__global__ __launch_bounds__(128) void fused_main(
    const unsigned short* __restrict__ xth,  // [N][2][32] fp16
    const unsigned short* __restrict__ Wrh,  // [25][4][64][8] fp16 (frag order)
    const float* __restrict__ bias,          // [64]
    const int* __restrict__ nidx,            // [N][25][3]
    const float* __restrict__ nw,            // [N][25][3]
    float* __restrict__ out,                 // [2][64][N] fp32
    int N)
{
    const int tid = threadIdx.x;
    const int n0 = blockIdx.x * 32;
    const int wv = tid >> 6;           // batch half b
    const int l = tid & 63;
    const int l31 = l & 31, lh = l >> 5;

    const int n = n0 + l31;
    const int nc = (n < N) ? n : (N - 1);
    const int*   ib = nidx + (size_t)nc * 75;
    const float* wb = nw   + (size_t)nc * 75;
    // gather bases: + j*64 halfwords per gather; cg0 = bytes [lh*16, +16),
    // cg1 = bytes [32 + lh*16, +16) of this b-half's 64B row
    const unsigned short* xg0 = xth + wv * 32 + lh * 8;
    const unsigned short* xg1 = xth + wv * 32 + 16 + lh * 8;

    int3   ri[2];
    float3 rw[2];
    unsigned int rwh[2][3];
    uint4  rg0[2][3], rg1[2][3];

    f32x16 acc0, acc1;
#pragma unroll
    for (int i = 0; i < 16; ++i) { acc0[i] = 0.f; acc1[i] = 0.f; }

    // ---- prologue: idx/w slices 0,1 -> gathers 0,1; idx/w 2,3 in flight ----
    {
        ri[0] = *reinterpret_cast<const int3*>(ib + 0);
        rw[0] = *reinterpret_cast<const float3*>(wb + 0);
        ri[1] = *reinterpret_cast<const int3*>(ib + 3);
        rw[1] = *reinterpret_cast<const float3*>(wb + 3);
#pragma unroll
        for (int s = 0; s < 2; ++s) {
            rg0[s][0] = *reinterpret_cast<const uint4*>(xg0 + ri[s].x * 64);
            rg1[s][0] = *reinterpret_cast<const uint4*>(xg1 + ri[s].x * 64);
            rg0[s][1] = *reinterpret_cast<const uint4*>(xg0 + ri[s].y * 64);
            rg1[s][1] = *reinterpret_cast<const uint4*>(xg1 + ri[s].y * 64);
            rg0[s][2] = *reinterpret_cast<const uint4*>(xg0 + ri[s].z * 64);
            rg1[s][2] = *reinterpret_cast<const uint4*>(xg1 + ri[s].z * 64);
            rwh[s][0] = pack2h(rw[s].x, rw[s].x);
            rwh[s][1] = pack2h(rw[s].y, rw[s].y);
            rwh[s][2] = pack2h(rw[s].z, rw[s].z);
        }
        ri[0] = *reinterpret_cast<const int3*>(ib + 6);
        rw[0] = *reinterpret_cast<const float3*>(wb + 6);
        ri[1] = *reinterpret_cast<const int3*>(ib + 9);
        rw[1] = *reinterpret_cast<const float3*>(wb + 9);
    }

#define WSUM(DST, RG, W0, W1, W2)                                              \
    do {                                                                       \
        uint4 v0 = RG[0], v1 = RG[1], v2 = RG[2];                              \
        U2H2 c;                                                                \
        c.h = __hfma2(u_as_h2(v0.x), W0,                                       \
              __hfma2(u_as_h2(v1.x), W1, __hmul2(u_as_h2(v2.x), W2)));         \
        DST.x = c.u;                                                           \
        c.h = __hfma2(u_as_h2(v0.y), W0,                                       \
              __hfma2(u_as_h2(v1.y), W1, __hmul2(u_as_h2(v2.y), W2)));         \
        DST.y = c.u;                                                           \
        c.h = __hfma2(u_as_h2(v0.z), W0,                                       \
              __hfma2(u_as_h2(v1.z), W1, __hmul2(u_as_h2(v2.z), W2)));         \
        DST.z = c.u;                                                           \
        c.h = __hfma2(u_as_h2(v0.w), W0,                                       \
              __hfma2(u_as_h2(v1.w), W1, __hmul2(u_as_h2(v2.w), W2)));         \
        DST.w = c.u;                                                           \
    } while (0)

#pragma unroll
    for (int k = 0; k < 25; ++k) {
        const int gb = k & 1;

        // A-fragments for slice k (4 coalesced 1KB wave-loads, L1/L2-hot);
        // issued first so the VALU below covers their latency
        const unsigned short* wk = Wrh + k * 2048 + l * 8;
        uint4 a0 = *reinterpret_cast<const uint4*>(wk + 0 * 512);
        uint4 a1 = *reinterpret_cast<const uint4*>(wk + 1 * 512);
        uint4 a2 = *reinterpret_cast<const uint4*>(wk + 2 * 512);
        uint4 a3 = *reinterpret_cast<const uint4*>(wk + 3 * 512);

        // weighted fp16 sums -> B-fragments (in-register, lane-local weights)
        __half2 w0 = u_as_h2(rwh[gb][0]), w1 = u_as_h2(rwh[gb][1]),
                w2 = u_as_h2(rwh[gb][2]);
        uint4 pb0, pb1;
        WSUM(pb0, rg0[gb], w0, w1, w2);
        WSUM(pb1, rg1[gb], w0, w1, w2);

        // refill: gathers(k+2) from prefetched idx; idx/w(k+4)
        if (k + 2 < 25) {
            rg0[gb][0] = *reinterpret_cast<const uint4*>(xg0 + ri[gb].x * 64);
            rg1[gb][0] = *reinterpret_cast<const uint4*>(xg1 + ri[gb].x * 64);
            rg0[gb][1] = *reinterpret_cast<const uint4*>(xg0 + ri[gb].y * 64);
            rg1[gb][1] = *reinterpret_cast<const uint4*>(xg1 + ri[gb].y * 64);
            rg0[gb][2] = *reinterpret_cast<const uint4*>(xg0 + ri[gb].z * 64);
            rg1[gb][2] = *reinterpret_cast<const uint4*>(xg1 + ri[gb].z * 64);
            rwh[gb][0] = pack2h(rw[gb].x, rw[gb].x);
            rwh[gb][1] = pack2h(rw[gb].y, rw[gb].y);
            rwh[gb][2] = pack2h(rw[gb].z, rw[gb].z);
            int ka = (k + 4 <= 24) ? k + 4 : 24;
            ri[gb] = *reinterpret_cast<const int3*>(ib + ka * 3);
            rw[gb] = *reinterpret_cast<const float3*>(wb + ka * 3);
        }

        // MFMA: acc[og] += A[og][cg] x B[cg]
        {
            half8 bf0 = __builtin_bit_cast(half8, pb0);
            half8 bf1 = __builtin_bit_cast(half8, pb1);
            acc0 = __builtin_amdgcn_mfma_f32_32x32x16_f16(
                __builtin_bit_cast(half8, a0), bf0, acc0, 0, 0, 0);
            acc0 = __builtin_amdgcn_mfma_f32_32x32x16_f16(
                __builtin_bit_cast(half8, a1), bf1, acc0, 0, 0, 0);
            acc1 = __builtin_amdgcn_mfma_f32_32x32x16_f16(
                __builtin_bit_cast(half8, a2), bf0, acc1, 0, 0, 0);
            acc1 = __builtin_amdgcn_mfma_f32_32x32x16_f16(
                __builtin_bit_cast(half8, a3), bf1, acc1, 0, 0, 0);
        }
    }
#undef WSUM

    // ---- epilogue: bias + coalesced store ----
    // D: col = l&31 = n-local; row r -> o = og*32 + (r&3) + 8*(r>>2) + 4*lh
    if (n < N) {
#pragma unroll
        for (int r = 0; r < 16; ++r) {
            int o = (r & 3) + 8 * (r >> 2) + 4 * lh;
            out[((size_t)wv * 64 + o) * N + n] = acc0[r] + bias[o];
        }
#pragma unroll
        for (int r = 0; r < 16; ++r) {
            int o = 32 + (r & 3) + 8 * (r >> 2) + 4 * lh;
            out[((size_t)wv * 64 + o) * N + n] = acc1[r] + bias[o];
        }
    }
}

extern "C" void kernel_launch(void* const* d_in, const int* in_sizes, int n_in,
                              void* d_out, int out_size, void* d_ws, size_t ws_size,
                              hipStream_t stream) {
    const float* x    = (const float*)d_in[0];   // (2,32,N)
    const float* nw   = (const float*)d_in[1];   // (N,25,3)
    const float* W    = (const float*)d_in[2];   // (64,800)
    const float* bias = (const float*)d_in[3];   // (64,)
    const int*   nidx = (const int*)d_in[4];     // (N,25,3)
    float* out = (float*)d_out;

    int N = in_sizes[0] / 64;  // B*C = 64

    unsigned short* xth = (unsigned short*)d_ws;      // [N][2][32] fp16
    unsigned short* Wrh = xth + (size_t)N * 64;       // [25][4][64][8] fp16

    int nT = (N + 63) / 64;
    prep_all<<<nT + 25, 256, 0, stream>>>(x, W, xth, Wrh, N, nT);

    fused_main<<<(N + 31) / 32, 128, 0, stream>>>(xth, Wrh, bias, nidx, nw, out, N);
}

// Round 18
// 58.101 us; speedup vs baseline: 1.8196x; 1.8196x over previous
//
#include <hip/hip_runtime.h>
#include <hip/hip_fp16.h>

typedef __attribute__((ext_vector_type(8))) _Float16 half8;
typedef __attribute__((ext_vector_type(4))) float f32x4;

union U2H2 { unsigned int u; __half2 h; };

static __device__ __forceinline__ unsigned int pack2h(float a, float b) {
    U2H2 c; c.h = __floats2half2_rn(a, b); return c.u;
}
static __device__ __forceinline__ __half2 u_as_h2(unsigned int u) {
    U2H2 c; c.u = u; return c.h;
}
static __device__ __forceinline__ __half2 hi16(unsigned int u) {
    return u_as_h2(__builtin_amdgcn_perm(u, u, 0x03020302u));
}

// swizzle: slot' = slot ^ (row&3) ^ ((row>>2)&3) ^ ((row>>5)&1)
// <=2-way (free) for the 8-lane paired-line writes, 4-lane B writes, and
// 16-consecutive-row MFMA fragment reads
#define SWZ(row, slot) \
    ((slot) ^ ((row) & 3) ^ (((row) >> 2) & 3) ^ (((row) >> 5) & 1))

// fence LDS + barrier WITHOUT draining vmcnt (prefetched loads stay in flight)
#define LDS_BARRIER()                                                \
    do {                                                             \
        asm volatile("s_waitcnt lgkmcnt(0)" ::: "memory");           \
        __builtin_amdgcn_s_barrier();                                \
        __builtin_amdgcn_sched_barrier(0);                           \
    } while (0)

// Prep: blocks [0,nT): transpose x -> xth [N][2][32] fp16 (b-halves share a
// 128B line); blocks [nT,nT+25): repack W -> Wrh[k][o][c] fp16.
__global__ __launch_bounds__(256) void prep_all(const float* __restrict__ x,
                                                const float* __restrict__ W,
                                                unsigned short* __restrict__ xth,
                                                unsigned short* __restrict__ Wrh,
                                                int N, int nT) {
    int bid = blockIdx.x, tid = threadIdx.x;
    if (bid >= nT) {
        int k = bid - nT;  // 0..24
#pragma unroll
        for (int it = 0; it < 8; ++it) {
            int r = tid + 256 * it;          // 0..2047 = o*32+c
            int o = r >> 5, c = r & 31;
            __half h = __float2half(W[o * 800 + c * 25 + k]);
            Wrh[k * 2048 + r] = *reinterpret_cast<unsigned short*>(&h);
        }
        return;
    }
    __shared__ float t[2][32][65];
    int n0 = bid * 64;
#pragma unroll
    for (int i = 0; i < 16; ++i) {
        int e = tid + 256 * i;               // [2][32][64]
        int b = e >> 11, c = (e >> 6) & 31, nl = e & 63;
        int n = n0 + nl;
        t[b][c][nl] = (n < N) ? x[(size_t)(b * 32 + c) * N + n] : 0.f;
    }
    __syncthreads();
    int nl = tid >> 2, q = tid & 3, n = n0 + nl;
    if (n < N) {
#pragma unroll
        for (int b = 0; b < 2; ++b) {
            uint4 p;
            p.x = pack2h(t[b][q * 8 + 0][nl], t[b][q * 8 + 1][nl]);
            p.y = pack2h(t[b][q * 8 + 2][nl], t[b][q * 8 + 3][nl]);
            p.z = pack2h(t[b][q * 8 + 4][nl], t[b][q * 8 + 5][nl]);
            p.w = pack2h(t[b][q * 8 + 6][nl], t[b][q * 8 + 7][nl]);
            *reinterpret_cast<uint4*>(xth + ((size_t)n * 64 + b * 32 + q * 8)) = p;
        }
    }
}

// Fused gather + einsum + MFMA + bias. 32-n tile; 8 lanes per (n,t) read the
// full 128B pair-line (both b halves) -> every requested byte used. Padded
// [nl][26][4] idx table -> one ds_read_b128 per thread-period.
__global__ __launch_bounds__(256) void fused_main(
    const unsigned short* __restrict__ xth,  // [N][2][32] fp16
    const unsigned short* __restrict__ Wrh,  // [25][64][32] fp16
    const float* __restrict__ bias,          // [64]
    const int* __restrict__ nidx,            // [N][25][3]
    const float* __restrict__ nw,            // [N][25][3]
    float* __restrict__ out,                 // [2][64][N] fp32
    int N)
{
    __shared__ unsigned int idxw[32 * 104];              // [nl][26][4]: j | half(w)<<16
    __shared__ __align__(16) unsigned char sA[2][4096];  // dbuf: 64 rows (2b x 32n) x 64B
    __shared__ __align__(16) unsigned char sB[2][4096];  // dbuf: 64 o-rows x 64B

    const int tid = threadIdx.x;
    const int n0 = blockIdx.x * 32;

    // ---- zero idx table (pads + slice 25), then fill slices 0..24 ----
#pragma unroll
    for (int it = 0; it < 13; ++it) {
        int e = tid + 256 * it;
        if (e < 3328) idxw[e] = 0u;
    }
    __syncthreads();
#pragma unroll
    for (int it = 0; it < 10; ++it) {
        int e = tid + 256 * it;
        if (e < 2400) {
            int nl = e / 75, r = e - nl * 75;
            int kk = r / 3, t = r - kk * 3;
            int n = n0 + nl;
            unsigned int u = 0;
            if (n < N) {
                size_t s = (size_t)n0 * 75 + e;
                int j = nidx[s];
                __half hw = __float2half(nw[s]);
                u = (unsigned int)j |
                    ((unsigned int)*reinterpret_cast<unsigned short*>(&hw) << 16);
            }
            idxw[nl * 104 + kk * 4 + t] = u;
        }
    }
    __syncthreads();

    const int nl = tid >> 3;                   // n-row 0..31 this thread gathers
    const int p8 = tid & 7;                    // 16B slice of the 128B pair-line
    const int grow = (p8 >> 2) * 32 + nl;      // sA row = b*32 + nl
    const int gq = p8 & 3;                     // c-quad within the 64B half
    const int wr_off = grow * 64 + (SWZ(grow, gq) << 4);

    // sB staging: thread t -> o-row t>>2, c-quad t&3
    const int sbo = (tid >> 2) * 64 + (SWZ((tid >> 2), (tid & 3)) << 4);

    const int l = tid & 63, wv = tid >> 6, c16 = l & 15, g = l >> 4;
    const int arow = 16 * wv + c16;
    const int rd_a = arow * 64 + (SWZ(arow, g) << 4);

    const unsigned short* xg = xth + p8 * 8;   // + j*64 per gather
    const unsigned int* iprow = &idxw[nl * 104];

    unsigned int ru[3][3];
    uint4 rg[3][3];
    uint4 rB;

    f32x4 acc[4];
#pragma unroll
    for (int ot = 0; ot < 4; ++ot) acc[ot] = (f32x4){0.f, 0.f, 0.f, 0.f};

    // ---- prologue: B(0); idx+gathers for slices 0..2 ----
    rB = *reinterpret_cast<const uint4*>(Wrh + tid * 8);
#pragma unroll
    for (int kk = 0; kk < 3; ++kk) {
        uint4 iq = *reinterpret_cast<const uint4*>(iprow + kk * 4);
        ru[kk][0] = iq.x; ru[kk][1] = iq.y; ru[kk][2] = iq.z;
    }
#pragma unroll
    for (int kk = 0; kk < 3; ++kk)
#pragma unroll
        for (int t = 0; t < 3; ++t)
            rg[kk][t] = *reinterpret_cast<const uint4*>(xg + (ru[kk][t] & 0xffffu) * 64);

#pragma unroll
    for (int k = 0; k < 25; ++k) {
        const int gb = k % 3, buf = k & 1;

        // consume rB -> sB[buf]; refill B(k+1)
        *reinterpret_cast<uint4*>(&sB[buf][sbo]) = rB;
        if (k + 1 < 25)
            rB = *reinterpret_cast<const uint4*>(Wrh + (k + 1) * 2048 + tid * 8);

        // weighted fp16 sum of slice k's 3 gathered pair-lines -> sA[buf]
        {
            __half2 w0 = hi16(ru[gb][0]), w1 = hi16(ru[gb][1]), w2 = hi16(ru[gb][2]);
            uint4 v0 = rg[gb][0], v1 = rg[gb][1], v2 = rg[gb][2];
            uint4 pk; U2H2 c;
            c.h = __hfma2(u_as_h2(v0.x), w0, __hfma2(u_as_h2(v1.x), w1, __hmul2(u_as_h2(v2.x), w2)));
            pk.x = c.u;
            c.h = __hfma2(u_as_h2(v0.y), w0, __hfma2(u_as_h2(v1.y), w1, __hmul2(u_as_h2(v2.y), w2)));
            pk.y = c.u;
            c.h = __hfma2(u_as_h2(v0.z), w0, __hfma2(u_as_h2(v1.z), w1, __hmul2(u_as_h2(v2.z), w2)));
            pk.z = c.u;
            c.h = __hfma2(u_as_h2(v0.w), w0, __hfma2(u_as_h2(v1.w), w1, __hmul2(u_as_h2(v2.w), w2)));
            pk.w = c.u;
            *reinterpret_cast<uint4*>(&sA[buf][wr_off]) = pk;
        }

        // idx quad for slice k+3 (one b128; drained by the barrier fence)
        uint4 niq;
        {
            int ka = (k + 3 < 25) ? k + 3 : 25;   // 25 = zero pad slice
            niq = *reinterpret_cast<const uint4*>(iprow + ka * 4);
        }

        // one barrier: sA/sB visible + idx ready; vmem prefetch stays in flight
        LDS_BARRIER();

        // issue gathers for slice k+3 immediately (addresses ready, no wait)
        if (k + 3 < 25) {
            ru[gb][0] = niq.x; ru[gb][1] = niq.y; ru[gb][2] = niq.z;
#pragma unroll
            for (int t = 0; t < 3; ++t)
                rg[gb][t] = *reinterpret_cast<const uint4*>(xg + (ru[gb][t] & 0xffffu) * 64);
        }

        // MFMA: A rows 16wv.., B shared slice
        {
            half8 af = *reinterpret_cast<const half8*>(&sA[buf][rd_a]);
#pragma unroll
            for (int ot = 0; ot < 4; ++ot) {
                int orow = ot * 16 + c16;
                half8 bf = *reinterpret_cast<const half8*>(
                    &sB[buf][orow * 64 + (SWZ(orow, g) << 4)]);
                acc[ot] = __builtin_amdgcn_mfma_f32_16x16x32_f16(af, bf, acc[ot], 0, 0, 0);
            }
        }
    }

    // ---- epilogue: bias + store (D: o = ot*16+c16, row = 16wv+4g+i) ----
#pragma unroll
    for (int ot = 0; ot < 4; ++ot) {
        int o = ot * 16 + c16;
        float bv = bias[o];
#pragma unroll
        for (int i = 0; i < 4; ++i) {
            int mrow = 16 * wv + 4 * g + i;
            int b = mrow >> 5, nn = n0 + (mrow & 31);
            if (nn < N) out[((size_t)b * 64 + o) * N + nn] = acc[ot][i] + bv;
        }
    }
}

extern "C" void kernel_launch(void* const* d_in, const int* in_sizes, int n_in,
                              void* d_out, int out_size, void* d_ws, size_t ws_size,
                              hipStream_t stream) {
    const float* x    = (const float*)d_in[0];   // (2,32,N)
    const float* nw   = (const float*)d_in[1];   // (N,25,3)
    const float* W    = (const float*)d_in[2];   // (64,800)
    const float* bias = (const float*)d_in[3];   // (64,)
    const int*   nidx = (const int*)d_in[4];     // (N,25,3)
    float* out = (float*)d_out;

    int N = in_sizes[0] / 64;  // B*C = 64

    unsigned short* xth = (unsigned short*)d_ws;      // [N][2][32] fp16
    unsigned short* Wrh = xth + (size_t)N * 64;       // [25][64][32] fp16

    int nT = (N + 63) / 64;
    prep_all<<<nT + 25, 256, 0, stream>>>(x, W, xth, Wrh, N, nT);

    fused_main<<<(N + 31) / 32, 256, 0, stream>>>(xth, Wrh, bias, nidx, nw, out, N);
}